// Round 3
// baseline (195.468 us; speedup 1.0000x reference)
//
#include <hip/hip_runtime.h>
#include <math.h>

// ---- nearest-neighbor LUT: 8192 floats over d in [-0.2, 1.27456), h=1.8e-4 ----
// index i = (int)((d - LO) * INVH), value = f(center of cell i). f==0 (to 1e-12)
// outside the band, so out-of-range indices are simply skipped (exec-masked).
#define NLUT    8192
#define LUT_LO  (-0.2)
#define LUT_H   (1.8e-4)
#define INVH    5555.5555555555f
#define BAND_LO (-0.35f)
#define BAND_HI (1.28f)

// ---- ws layout (bytes) ---- (total == round-0 footprint, known safe)
#define WS_LUT    0          // float[8192]    32768
#define WS_TH2T   32768      // float[36864]   147456 -> 180224
#define WS_XS     180224     // float[262144]  1048576 -> 1228800  (xs, later c2buf)
#define WS_MASK   1228800    // u64[4096]      32768  -> 1261568
#define WS_SUMS1  1261568    // float[128]     512    -> 1262080
#define WS_SUMS2  1262080    // float[128]     512    -> 1262592
#define WS_MM     1262592    // u32[2]         8      -> 1262600
#define WS_TOTAL  1262600

__device__ __forceinline__ double f_exact(double d) {
    const double nvt = 1.5 * 0.026;
    double a1 = d / nvt;         a1 = fmin(fmax(a1, -30.0), 30.0);
    double a2 = (d - 0.1) / nvt; a2 = fmin(fmax(a2, -30.0), 30.0);
    double s1 = log1p(exp(a1));
    double s2 = log1p(exp(a2));
    return 0.0005625 * (s1 * s1 - s2 * s2);
}

// K0: blk<32 LUT | blk<176 theta2 transpose + min/max | else prescaled xs (float4,
// channel-major natural layout -> fully coalesced both sides)
__global__ __launch_bounds__(256) void k0_prep(
    const float* __restrict__ x, const float* __restrict__ theta2,
    const float* __restrict__ psc, const float* __restrict__ psh,
    float* __restrict__ lutg, float* __restrict__ th2t,
    float* __restrict__ xs, unsigned* __restrict__ mm)
{
    int blk = blockIdx.x, tid = threadIdx.x;
    if (blk < 32) {
        int i = blk * 256 + tid;                       // 0..8191
        double d = LUT_LO + ((double)i + 0.5) * LUT_H; // cell center
        lutg[i] = (float)f_exact(d);
    } else if (blk < 176) {
        int i = (blk - 32) * 256 + tid;                // 0..36863
        int p = i & 63, k = i >> 6;
        float v = theta2[p * 576 + k];
        th2t[k * 64 + p] = v;
        __shared__ float smin[256], smax[256];
        smin[tid] = v; smax[tid] = v;
        __syncthreads();
        for (int s = 128; s > 0; s >>= 1) {
            if (tid < s) {
                smin[tid] = fminf(smin[tid], smin[tid + s]);
                smax[tid] = fmaxf(smax[tid], smax[tid + s]);
            }
            __syncthreads();
        }
        if (tid == 0) {
            atomicMax(&mm[0], __float_as_uint(smax[0]));   // thetas > 0
            atomicMax(&mm[1], ~__float_as_uint(smin[0]));  // min via complement
        }
    } else {
        int i4 = (blk - 176) * 256 + tid;              // 0..65535
        float sc = psc[0] * INVH;
        float sh = (psh[0] - (float)LUT_LO) * INVH;
        float4 xv = ((const float4*)x)[i4];
        float4 o;
        o.x = fmaf(xv.x, sc, sh); o.y = fmaf(xv.y, sc, sh);
        o.z = fmaf(xv.z, sc, sh); o.w = fmaf(xv.w, sc, sh);
        ((float4*)xs)[i4] = o;
    }
}

// K1: dense conv1. grid 512 = b(4) x yp(16) x pg(8); wave = 2 planes, 2 rows.
// Coalesced 4B xs loads (channel-major), wave-uniform theta -> s_loads,
// exec-masked nearest-LUT gathers. BN1 partial sums fused.
__global__ __launch_bounds__(256) void k1_conv1(
    const float* __restrict__ xs, const float* __restrict__ theta1,
    const float* __restrict__ ls1, const float* __restrict__ lutg,
    float* __restrict__ rawb, float* __restrict__ sums1)
{
    __shared__ float lut[NLUT];
    {
        const float4* s = (const float4*)lutg;
        float4* d = (float4*)lut;
        for (int i = threadIdx.x; i < NLUT / 4; i += 256) d[i] = s[i];
    }
    __syncthreads();

    int blk = blockIdx.x;
    int pg = blk & 7;
    int yp = (blk >> 3) & 15;
    int b  = blk >> 7;
    int wv = __builtin_amdgcn_readfirstlane((int)threadIdx.x >> 6);
    int lane = threadIdx.x & 63;
    int r = lane >> 5, xc = lane & 31;
    int y = yp * 2 + r;
    int p0 = pg * 8 + wv * 2;

    // per-lane tap offsets (clamped addr) + validity sentinel
    int poff[9]; bool pval[9];
    #pragma unroll
    for (int t = 0; t < 9; ++t) {
        int ny = y + t / 3 - 1, nx = xc + t % 3 - 1;
        pval[t] = ((unsigned)ny < 32u) && ((unsigned)nx < 32u);
        int nyc = min(max(ny, 0), 31), nxc = min(max(nx, 0), 31);
        poff[t] = nyc * 32 + nxc;
    }

    const float* xsb = xs + b * 65536;
    const float* t0p = theta1 + p0 * 576;
    const float* t1p = t0p + 576;
    float ninvh = -INVH;
    float acc0 = 0.f, acc1 = 0.f;

    #pragma unroll 2
    for (int c = 0; c < 64; ++c) {
        const float* xrow = xsb + c * 1024;
        const float* ta = t0p + c * 9;
        const float* tb = t1p + c * 9;
        #pragma unroll
        for (int t = 0; t < 9; ++t) {
            float v = xrow[poff[t]];
            v = pval[t] ? v : -1e9f;               // 1 cndmask kills both planes
            float q0 = fmaf(ta[t], ninvh, v);      // theta via SGPR
            float q1 = fmaf(tb[t], ninvh, v);
            int i0 = (int)q0, i1 = (int)q1;
            if ((unsigned)i0 < (unsigned)NLUT) acc0 += lut[i0];
            if ((unsigned)i1 < (unsigned)NLUT) acc1 += lut[i1];
        }
    }

    float l1 = ls1[0];
    float r0 = l1 * acc0, r1 = l1 * acc1;
    int o = ((b * 64 + p0) * 32 + y) * 32 + xc;
    rawb[o]        = r0;
    rawb[o + 1024] = r1;

    // fused BN1 partial sums: wave reduce, lane0 atomics
    float s0 = r0, q0s = r0 * r0, s1 = r1, q1s = r1 * r1;
    for (int s = 32; s > 0; s >>= 1) {
        s0  += __shfl_xor(s0, s);
        q0s += __shfl_xor(q0s, s);
        s1  += __shfl_xor(s1, s);
        q1s += __shfl_xor(q1s, s);
    }
    if (lane == 0) {
        atomicAdd(&sums1[p0], s0);
        atomicAdd(&sums1[64 + p0], q0s);
        atomicAdd(&sums1[p0 + 1], s1);
        atomicAdd(&sums1[64 + p0 + 1], q1s);
    }
}

// K3: BN1 apply in place on rawb (=d_out) + activity masks. float4.
__global__ __launch_bounds__(256) void k3_bn1mask(float* __restrict__ v2,
    const float* __restrict__ sums1, const float* __restrict__ g1,
    const float* __restrict__ b1, const unsigned* __restrict__ mm,
    unsigned long long* __restrict__ masks)
{
    int i4 = blockIdx.x * 256 + threadIdx.x;       // 0..65535
    int idx = i4 * 4;
    int c = (idx >> 10) & 63;
    int b = idx >> 16;
    float m   = sums1[c] * (1.f / 4096.f);
    float var = sums1[64 + c] * (1.f / 4096.f) - m * m;
    var = fmaxf(var, 0.f);
    float rstd = rsqrtf(var + 1e-5f);
    float sc = rstd * g1[c];
    float sh = b1[c] - m * sc;
    float4 v = ((float4*)v2)[i4];
    v.x = fmaf(v.x, sc, sh); v.y = fmaf(v.y, sc, sh);
    v.z = fmaf(v.z, sc, sh); v.w = fmaf(v.w, sc, sh);
    ((float4*)v2)[i4] = v;
    float tmax = __uint_as_float(mm[0]);
    float tmin = __uint_as_float(~mm[1]);
    float wlo = tmin + BAND_LO, whi = tmax + BAND_HI;
    unsigned long long bit = 1ull << c;
    float vv[4] = {v.x, v.y, v.z, v.w};
    #pragma unroll
    for (int k = 0; k < 4; ++k) {
        if (vv[k] > wlo && vv[k] < whi)
            atomicOr(&masks[b * 1024 + ((idx + k) & 1023)], bit);
    }
}

// K4: sparse conv2. grid 1024, wave per pixel, lane = output plane. Exact f32 eval.
__global__ __launch_bounds__(256) void k4_conv2(const float* __restrict__ v2,
    const float* __restrict__ th2t, const unsigned long long* __restrict__ masks,
    const float* __restrict__ ls2, float* __restrict__ c2, float* __restrict__ sums2)
{
    int wv = __builtin_amdgcn_readfirstlane((int)threadIdx.x >> 6);
    int lane = threadIdx.x & 63;
    int P = blockIdx.x * 4 + wv;                   // 0..4095
    int b = P >> 10, rem = P & 1023;
    int y = rem >> 5, xq = rem & 31;
    float l2 = ls2[0];
    const float inv_nvt = (float)(1.0 / (1.5 * 0.026));
    float acc = 0.f;

    #pragma unroll
    for (int j = 0; j < 9; ++j) {
        int ny = y + j / 3 - 1, nx = xq + j % 3 - 1;
        if ((unsigned)ny < 32u && (unsigned)nx < 32u) {
            unsigned long long mk = masks[b * 1024 + ny * 32 + nx];
            while (mk) {
                int c = __ffsll((long long)mk) - 1;
                mk &= mk - 1;
                float v  = v2[((b * 64 + c) * 32 + ny) * 32 + nx];  // wave-uniform
                float th = th2t[(c * 9 + j) * 64 + lane];           // coalesced
                float d = v - th;
                if (d > BAND_LO && d < BAND_HI) {
                    float a1 = fminf(fmaxf(d * inv_nvt, -30.f), 30.f);
                    float a2 = fminf(fmaxf((d - 0.1f) * inv_nvt, -30.f), 30.f);
                    float s1 = __logf(1.f + __expf(a1));
                    float s2 = __logf(1.f + __expf(a2));
                    acc += (s1 * s1 - s2 * s2);
                }
            }
        }
    }
    float r2 = 0.0005625f * l2 * acc;
    c2[((b * 64 + lane) * 32 + y) * 32 + xq] = r2;

    __shared__ float ss[256], sq[256];
    ss[threadIdx.x] = r2; sq[threadIdx.x] = r2 * r2;
    __syncthreads();
    if (threadIdx.x < 64) {
        float a  = ss[threadIdx.x] + ss[threadIdx.x + 64] + ss[threadIdx.x + 128] + ss[threadIdx.x + 192];
        float qq = sq[threadIdx.x] + sq[threadIdx.x + 64] + sq[threadIdx.x + 128] + sq[threadIdx.x + 192];
        atomicAdd(&sums2[threadIdx.x], a);
        atomicAdd(&sums2[64 + threadIdx.x], qq);
    }
}

// K6: BN2 apply + residual, c2buf -> d_out. float4.
__global__ __launch_bounds__(256) void k6_final(float* __restrict__ out,
    const float* __restrict__ x, const float* __restrict__ c2,
    const float* __restrict__ sums2,
    const float* __restrict__ g2, const float* __restrict__ b2)
{
    int i4 = blockIdx.x * 256 + threadIdx.x;       // 0..65535
    int idx = i4 * 4;
    int p = (idx >> 10) & 63;
    float m   = sums2[p] * (1.f / 4096.f);
    float var = sums2[64 + p] * (1.f / 4096.f) - m * m;
    var = fmaxf(var, 0.f);
    float rstd = rsqrtf(var + 1e-5f);
    float sc = rstd * g2[p];
    float sh = b2[p] - m * sc;
    float4 c = ((const float4*)c2)[i4];
    float4 xv = ((const float4*)x)[i4];
    float4 o;
    o.x = fmaf(c.x, sc, sh) + xv.x;
    o.y = fmaf(c.y, sc, sh) + xv.y;
    o.z = fmaf(c.z, sc, sh) + xv.z;
    o.w = fmaf(c.w, sc, sh) + xv.w;
    ((float4*)out)[i4] = o;
}

extern "C" void kernel_launch(void* const* d_in, const int* in_sizes, int n_in,
                              void* d_out, int out_size, void* d_ws, size_t ws_size,
                              hipStream_t stream)
{
    const float* x   = (const float*)d_in[0];
    const float* th1 = (const float*)d_in[1];
    const float* th2 = (const float*)d_in[2];
    const float* psc = (const float*)d_in[3];
    const float* psh = (const float*)d_in[4];
    const float* l1  = (const float*)d_in[5];
    const float* l2  = (const float*)d_in[6];
    const float* g1  = (const float*)d_in[7];
    const float* b1  = (const float*)d_in[8];
    const float* g2  = (const float*)d_in[9];
    const float* b2  = (const float*)d_in[10];
    float* out = (float*)d_out;
    char* ws = (char*)d_ws;
    if (ws_size < (size_t)WS_TOTAL) return;  // defensive: leave output poisoned

    float* lutg  = (float*)(ws + WS_LUT);
    float* th2t  = (float*)(ws + WS_TH2T);
    float* xsbuf = (float*)(ws + WS_XS);     // xs for K1; reused as c2buf for K4/K6
    unsigned long long* masks = (unsigned long long*)(ws + WS_MASK);
    float* sums1 = (float*)(ws + WS_SUMS1);
    float* sums2 = (float*)(ws + WS_SUMS2);
    unsigned* mm = (unsigned*)(ws + WS_MM);

    float* rawb = out;   // conv1 raw / BN1-applied activations live in d_out
    float* c2   = xsbuf; // xs dead after K1 -> reuse as conv2 output buffer

    // one memset covers masks + sums1 + sums2 + mm
    hipMemsetAsync(ws + WS_MASK, 0, WS_TOTAL - WS_MASK, stream);

    k0_prep   <<<432,  256, 0, stream>>>(x, th2, psc, psh, lutg, th2t, xsbuf, mm);
    k1_conv1  <<<512,  256, 0, stream>>>(xsbuf, th1, l1, lutg, rawb, sums1);
    k3_bn1mask<<<256,  256, 0, stream>>>(rawb, sums1, g1, b1, mm, masks);
    k4_conv2  <<<1024, 256, 0, stream>>>(rawb, th2t, masks, l2, c2, sums2);
    k6_final  <<<256,  256, 0, stream>>>(out, x, c2, sums2, g2, b2);
}

// Round 4
// 105.492 us; speedup vs baseline: 1.8529x; 1.8529x over previous
//
#include <hip/hip_runtime.h>
#include <math.h>

// ---- nearest-neighbor LUT: 8192 floats over d in [-0.2, 1.27456), h=1.8e-4 ----
// index = (d - LO) * INVH, clamped to [0, 8191]. f==0 (to ~1e-10) outside the
// band, so clamped lanes read edge cells (~0) and broadcast (no bank conflict).
#define NLUT    8192
#define LUT_LO  (-0.2)
#define LUT_H   (1.8e-4)
#define INVH    5555.5555555555f
#define QMAXF   8191.0f
#define BAND_LO (-0.35f)
#define BAND_HI (1.28f)

// ---- ws layout (bytes) ---- total == 1,262,600 (known-safe footprint)
#define WS_LUT    0          // float[8192]    32768
#define WS_TH2T   32768      // float[36864]   147456 -> 180224
#define WS_C2     180224     // float[262144]  1048576 -> 1228800
                             //   th1s (float[36864]) aliases the START of C2;
                             //   th1s is dead after k1, c2 written in k4.
#define WS_MASK   1228800    // u64[4096]      32768  -> 1261568
#define WS_SUMS1  1261568    // float[128]     512    -> 1262080
#define WS_SUMS2  1262080    // float[128]     512    -> 1262592
#define WS_MM     1262592    // u32[2]         8      -> 1262600
#define WS_TOTAL  1262600

__device__ __forceinline__ double f_exact(double d) {
    const double nvt = 1.5 * 0.026;
    double a1 = d / nvt;         a1 = fmin(fmax(a1, -30.0), 30.0);
    double a2 = (d - 0.1) / nvt; a2 = fmin(fmax(a2, -30.0), 30.0);
    double s1 = log1p(exp(a1));
    double s2 = log1p(exp(a2));
    return 0.0005625 * (s1 * s1 - s2 * s2);
}

// K0: blk<32 LUT | blk<176 theta2 transpose + min/max | else th1s pre-scale
__global__ __launch_bounds__(256) void k0_prep(
    const float* __restrict__ theta1, const float* __restrict__ theta2,
    const float* __restrict__ psh,
    float* __restrict__ lutg, float* __restrict__ th2t,
    float* __restrict__ th1s, unsigned* __restrict__ mm)
{
    int blk = blockIdx.x, tid = threadIdx.x;
    if (blk < 32) {
        int i = blk * 256 + tid;                       // 0..8191
        double d = LUT_LO + ((double)i + 0.5) * LUT_H; // cell center
        lutg[i] = (float)f_exact(d);
    } else if (blk < 176) {
        int i = (blk - 32) * 256 + tid;                // 0..36863
        int p = i & 63, k = i >> 6;
        float v = theta2[p * 576 + k];
        th2t[k * 64 + p] = v;
        __shared__ float smin[256], smax[256];
        smin[tid] = v; smax[tid] = v;
        __syncthreads();
        for (int s = 128; s > 0; s >>= 1) {
            if (tid < s) {
                smin[tid] = fminf(smin[tid], smin[tid + s]);
                smax[tid] = fmaxf(smax[tid], smax[tid + s]);
            }
            __syncthreads();
        }
        if (tid == 0) {
            atomicMax(&mm[0], __float_as_uint(smax[0]));   // thetas > 0
            atomicMax(&mm[1], ~__float_as_uint(smin[0]));  // min via complement
        }
    } else {
        int i = (blk - 176) * 256 + tid;               // 0..36863
        // index term: (psh - LO - theta1) * INVH ; x term added in k1
        th1s[i] = (psh[0] - (float)LUT_LO - theta1[i]) * INVH;
    }
}

// K1: dense conv1. grid 512 = b(4) x yp(16) x pg(8); wave = 2 planes, 2 rows.
// Raw-x coalesced 4B loads, wave-uniform pre-scaled theta -> s_loads,
// UNCONDITIONAL clamped LUT gathers (out-of-band -> edge-cell broadcast).
__global__ __launch_bounds__(256) void k1_conv1(
    const float* __restrict__ x, const float* __restrict__ th1s,
    const float* __restrict__ psc, const float* __restrict__ ls1,
    const float* __restrict__ lutg,
    float* __restrict__ rawb, float* __restrict__ sums1)
{
    __shared__ float lut[NLUT];
    {
        const float4* s = (const float4*)lutg;
        float4* d = (float4*)lut;
        for (int i = threadIdx.x; i < NLUT / 4; i += 256) d[i] = s[i];
    }
    __syncthreads();

    int blk = blockIdx.x;
    int pg = blk & 7;
    int yp = (blk >> 3) & 15;
    int b  = blk >> 7;
    int wv = __builtin_amdgcn_readfirstlane((int)threadIdx.x >> 6);
    int lane = threadIdx.x & 63;
    int r = lane >> 5, xc = lane & 31;
    int y = yp * 2 + r;
    int p0 = pg * 8 + wv * 2;

    // per-lane tap offsets (clamped addr) + validity
    int poff[9]; bool pval[9];
    #pragma unroll
    for (int t = 0; t < 9; ++t) {
        int ny = y + t / 3 - 1, nx = xc + t % 3 - 1;
        pval[t] = ((unsigned)ny < 32u) && ((unsigned)nx < 32u);
        int nyc = min(max(ny, 0), 31), nxc = min(max(nx, 0), 31);
        poff[t] = nyc * 32 + nxc;
    }

    const float* xb = x + b * 65536;
    const float* ta = th1s + p0 * 576;
    const float* tb = ta + 576;
    float SC = psc[0] * INVH;
    float acc0 = 0.f, acc1 = 0.f;

    #pragma unroll 2
    for (int c = 0; c < 64; ++c) {
        const float* xr = xb + c * 1024;
        float v[9];
        #pragma unroll
        for (int t = 0; t < 9; ++t) {
            float xv = xr[poff[t]];
            v[t] = pval[t] ? xv : 1e9f;   // sentinel -> clamps to lut[8191] ~ 0
        }
        const float* tap = ta + c * 9;
        const float* tbp = tb + c * 9;
        #pragma unroll
        for (int t = 0; t < 9; ++t) {
            float q0 = fmaf(v[t], SC, tap[t]);       // theta via SGPR
            q0 = fminf(fmaxf(q0, 0.f), QMAXF);       // -> v_med3
            acc0 += lut[(int)q0];
            float q1 = fmaf(v[t], SC, tbp[t]);
            q1 = fminf(fmaxf(q1, 0.f), QMAXF);
            acc1 += lut[(int)q1];
        }
    }

    float l1 = ls1[0];
    float r0 = l1 * acc0, r1 = l1 * acc1;
    int o = ((b * 64 + p0) * 32 + y) * 32 + xc;
    rawb[o]        = r0;
    rawb[o + 1024] = r1;

    // fused BN1 partial sums: wave reduce, lane0 atomics
    float s0 = r0, q0s = r0 * r0, s1 = r1, q1s = r1 * r1;
    for (int s = 32; s > 0; s >>= 1) {
        s0  += __shfl_xor(s0, s);
        q0s += __shfl_xor(q0s, s);
        s1  += __shfl_xor(s1, s);
        q1s += __shfl_xor(q1s, s);
    }
    if (lane == 0) {
        atomicAdd(&sums1[p0], s0);
        atomicAdd(&sums1[64 + p0], q0s);
        atomicAdd(&sums1[p0 + 1], s1);
        atomicAdd(&sums1[64 + p0 + 1], q1s);
    }
}

// K3: BN1 apply in place on rawb (=d_out) + activity masks. float4.
__global__ __launch_bounds__(256) void k3_bn1mask(float* __restrict__ v2,
    const float* __restrict__ sums1, const float* __restrict__ g1,
    const float* __restrict__ b1, const unsigned* __restrict__ mm,
    unsigned long long* __restrict__ masks)
{
    int i4 = blockIdx.x * 256 + threadIdx.x;       // 0..65535
    int idx = i4 * 4;
    int c = (idx >> 10) & 63;
    int b = idx >> 16;
    float m   = sums1[c] * (1.f / 4096.f);
    float var = sums1[64 + c] * (1.f / 4096.f) - m * m;
    var = fmaxf(var, 0.f);
    float rstd = rsqrtf(var + 1e-5f);
    float sc = rstd * g1[c];
    float sh = b1[c] - m * sc;
    float4 v = ((float4*)v2)[i4];
    v.x = fmaf(v.x, sc, sh); v.y = fmaf(v.y, sc, sh);
    v.z = fmaf(v.z, sc, sh); v.w = fmaf(v.w, sc, sh);
    ((float4*)v2)[i4] = v;
    float tmax = __uint_as_float(mm[0]);
    float tmin = __uint_as_float(~mm[1]);
    float wlo = tmin + BAND_LO, whi = tmax + BAND_HI;
    unsigned long long bit = 1ull << c;
    float vv[4] = {v.x, v.y, v.z, v.w};
    #pragma unroll
    for (int k = 0; k < 4; ++k) {
        if (vv[k] > wlo && vv[k] < whi)
            atomicOr(&masks[b * 1024 + ((idx + k) & 1023)], bit);
    }
}

// K4: sparse conv2. grid 1024, wave per pixel, lane = output plane. Exact f32 eval.
__global__ __launch_bounds__(256) void k4_conv2(const float* __restrict__ v2,
    const float* __restrict__ th2t, const unsigned long long* __restrict__ masks,
    const float* __restrict__ ls2, float* __restrict__ c2, float* __restrict__ sums2)
{
    int wv = __builtin_amdgcn_readfirstlane((int)threadIdx.x >> 6);
    int lane = threadIdx.x & 63;
    int P = blockIdx.x * 4 + wv;                   // 0..4095
    int b = P >> 10, rem = P & 1023;
    int y = rem >> 5, xq = rem & 31;
    float l2 = ls2[0];
    const float inv_nvt = (float)(1.0 / (1.5 * 0.026));
    float acc = 0.f;

    #pragma unroll
    for (int j = 0; j < 9; ++j) {
        int ny = y + j / 3 - 1, nx = xq + j % 3 - 1;
        if ((unsigned)ny < 32u && (unsigned)nx < 32u) {
            unsigned long long mk = masks[b * 1024 + ny * 32 + nx];
            while (mk) {
                int c = __ffsll((long long)mk) - 1;
                mk &= mk - 1;
                float v  = v2[((b * 64 + c) * 32 + ny) * 32 + nx];  // wave-uniform
                float th = th2t[(c * 9 + j) * 64 + lane];           // coalesced
                float d = v - th;
                if (d > BAND_LO && d < BAND_HI) {
                    float a1 = fminf(fmaxf(d * inv_nvt, -30.f), 30.f);
                    float a2 = fminf(fmaxf((d - 0.1f) * inv_nvt, -30.f), 30.f);
                    float s1 = __logf(1.f + __expf(a1));
                    float s2 = __logf(1.f + __expf(a2));
                    acc += (s1 * s1 - s2 * s2);
                }
            }
        }
    }
    float r2 = 0.0005625f * l2 * acc;
    c2[((b * 64 + lane) * 32 + y) * 32 + xq] = r2;

    __shared__ float ss[256], sq[256];
    ss[threadIdx.x] = r2; sq[threadIdx.x] = r2 * r2;
    __syncthreads();
    if (threadIdx.x < 64) {
        float a  = ss[threadIdx.x] + ss[threadIdx.x + 64] + ss[threadIdx.x + 128] + ss[threadIdx.x + 192];
        float qq = sq[threadIdx.x] + sq[threadIdx.x + 64] + sq[threadIdx.x + 128] + sq[threadIdx.x + 192];
        atomicAdd(&sums2[threadIdx.x], a);
        atomicAdd(&sums2[64 + threadIdx.x], qq);
    }
}

// K6: BN2 apply + residual, c2 -> d_out. float4.
__global__ __launch_bounds__(256) void k6_final(float* __restrict__ out,
    const float* __restrict__ x, const float* __restrict__ c2,
    const float* __restrict__ sums2,
    const float* __restrict__ g2, const float* __restrict__ b2)
{
    int i4 = blockIdx.x * 256 + threadIdx.x;       // 0..65535
    int idx = i4 * 4;
    int p = (idx >> 10) & 63;
    float m   = sums2[p] * (1.f / 4096.f);
    float var = sums2[64 + p] * (1.f / 4096.f) - m * m;
    var = fmaxf(var, 0.f);
    float rstd = rsqrtf(var + 1e-5f);
    float sc = rstd * g2[p];
    float sh = b2[p] - m * sc;
    float4 c = ((const float4*)c2)[i4];
    float4 xv = ((const float4*)x)[i4];
    float4 o;
    o.x = fmaf(c.x, sc, sh) + xv.x;
    o.y = fmaf(c.y, sc, sh) + xv.y;
    o.z = fmaf(c.z, sc, sh) + xv.z;
    o.w = fmaf(c.w, sc, sh) + xv.w;
    ((float4*)out)[i4] = o;
}

extern "C" void kernel_launch(void* const* d_in, const int* in_sizes, int n_in,
                              void* d_out, int out_size, void* d_ws, size_t ws_size,
                              hipStream_t stream)
{
    const float* x   = (const float*)d_in[0];
    const float* th1 = (const float*)d_in[1];
    const float* th2 = (const float*)d_in[2];
    const float* psc = (const float*)d_in[3];
    const float* psh = (const float*)d_in[4];
    const float* l1  = (const float*)d_in[5];
    const float* l2  = (const float*)d_in[6];
    const float* g1  = (const float*)d_in[7];
    const float* b1  = (const float*)d_in[8];
    const float* g2  = (const float*)d_in[9];
    const float* b2  = (const float*)d_in[10];
    float* out = (float*)d_out;
    char* ws = (char*)d_ws;
    if (ws_size < (size_t)WS_TOTAL) return;  // defensive: leave output poisoned

    float* lutg  = (float*)(ws + WS_LUT);
    float* th2t  = (float*)(ws + WS_TH2T);
    float* c2    = (float*)(ws + WS_C2);
    float* th1s  = (float*)(ws + WS_C2);     // aliases c2; dead after k1
    unsigned long long* masks = (unsigned long long*)(ws + WS_MASK);
    float* sums1 = (float*)(ws + WS_SUMS1);
    float* sums2 = (float*)(ws + WS_SUMS2);
    unsigned* mm = (unsigned*)(ws + WS_MM);

    float* rawb = out;   // conv1 raw / BN1-applied activations live in d_out

    // one memset covers masks + sums1 + sums2 + mm
    hipMemsetAsync(ws + WS_MASK, 0, WS_TOTAL - WS_MASK, stream);

    k0_prep   <<<320,  256, 0, stream>>>(th1, th2, psh, lutg, th2t, th1s, mm);
    k1_conv1  <<<512,  256, 0, stream>>>(x, th1s, psc, l1, lutg, rawb, sums1);
    k3_bn1mask<<<256,  256, 0, stream>>>(rawb, sums1, g1, b1, mm, masks);
    k4_conv2  <<<1024, 256, 0, stream>>>(rawb, th2t, masks, l2, c2, sums2);
    k6_final  <<<256,  256, 0, stream>>>(out, x, c2, sums2, g2, b2);
}

// Round 5
// 99.231 us; speedup vs baseline: 1.9698x; 1.0631x over previous
//
#include <hip/hip_runtime.h>
#include <math.h>

// ---- nearest-neighbor LUT: 8192 floats over d in [-0.2, 1.27456), h=1.8e-4 ----
// BYTE index = (d - LO) * INVH * 4, clamped to [0, 32764] (per-lane limit also
// encodes border validity: invalid taps clamp to lut[0] ~= 2e-8 ~ 0).
#define NLUT    8192
#define LUT_LO  (-0.2)
#define LUT_H   (1.8e-4)
#define INVH    5555.5555555555f
#define INVH4   22222.222222222f   // 4 * INVH (byte-scaled index)
#define BLIM    32764.0f           // (NLUT-1)*4
#define BAND_LO (-0.35f)
#define BAND_HI (1.28f)

// ---- ws layout (bytes) ---- total == 1,262,600 (known-safe footprint)
#define WS_LUT    0          // float[8192]    32768
#define WS_TH2T   32768      // float[36864]   147456 -> 180224
#define WS_C2     180224     // float[262144]  1048576 -> 1228800
                             //   th1s (float[36864]) aliases the START of C2;
                             //   th1s dead after k1, c2 written in k4.
#define WS_MASK   1228800    // u64[4096]      32768  -> 1261568
#define WS_SUMS1  1261568    // float[128]     512    -> 1262080
#define WS_SUMS2  1262080    // float[128]     512    -> 1262592
#define WS_MM     1262592    // u32[2]         8      -> 1262600
#define WS_TOTAL  1262600

__device__ __forceinline__ double f_exact(double d) {
    const double nvt = 1.5 * 0.026;
    double a1 = d / nvt;         a1 = fmin(fmax(a1, -30.0), 30.0);
    double a2 = (d - 0.1) / nvt; a2 = fmin(fmax(a2, -30.0), 30.0);
    double s1 = log1p(exp(a1));
    double s2 = log1p(exp(a2));
    return 0.0005625 * (s1 * s1 - s2 * s2);
}

// K0: blk<32 LUT | blk<176 theta2 transpose + min/max | else th1s pre-scale
__global__ __launch_bounds__(256) void k0_prep(
    const float* __restrict__ theta1, const float* __restrict__ theta2,
    const float* __restrict__ psh,
    float* __restrict__ lutg, float* __restrict__ th2t,
    float* __restrict__ th1s, unsigned* __restrict__ mm)
{
    int blk = blockIdx.x, tid = threadIdx.x;
    if (blk < 32) {
        int i = blk * 256 + tid;                       // 0..8191
        double d = LUT_LO + ((double)i + 0.5) * LUT_H; // cell center
        lutg[i] = (float)f_exact(d);
    } else if (blk < 176) {
        int i = (blk - 32) * 256 + tid;                // 0..36863
        int p = i & 63, k = i >> 6;
        float v = theta2[p * 576 + k];
        th2t[k * 64 + p] = v;
        __shared__ float smin[256], smax[256];
        smin[tid] = v; smax[tid] = v;
        __syncthreads();
        for (int s = 128; s > 0; s >>= 1) {
            if (tid < s) {
                smin[tid] = fminf(smin[tid], smin[tid + s]);
                smax[tid] = fmaxf(smax[tid], smax[tid + s]);
            }
            __syncthreads();
        }
        if (tid == 0) {
            atomicMax(&mm[0], __float_as_uint(smax[0]));   // thetas > 0
            atomicMax(&mm[1], ~__float_as_uint(smin[0]));  // min via complement
        }
    } else {
        int i = (blk - 176) * 256 + tid;               // 0..36863
        // byte-index term: (psh - LO - theta1) * INVH4 ; x term added in k1
        th1s[i] = (psh[0] - (float)LUT_LO - theta1[i]) * INVH4;
    }
}

// K1: dense conv1. grid 1024 = b(4) x yp(16) x pq(16); wave = 1 plane, 2 rows.
// 4 blocks/CU (16 waves/CU). Raw-x coalesced loads, wave-uniform pre-scaled
// theta -> s_loads, unconditional clamped LUT gathers; border folded into
// per-lane clamp limit (invalid -> lut[0] ~ 0). BN1 partial sums fused.
__global__ __launch_bounds__(256, 4) void k1_conv1(
    const float* __restrict__ x, const float* __restrict__ th1s,
    const float* __restrict__ psc, const float* __restrict__ ls1,
    const float* __restrict__ lutg,
    float* __restrict__ rawb, float* __restrict__ sums1)
{
    __shared__ float lut[NLUT];
    {
        const float4* s = (const float4*)lutg;
        float4* d = (float4*)lut;
        for (int i = threadIdx.x; i < NLUT / 4; i += 256) d[i] = s[i];
    }
    __syncthreads();

    int blk = blockIdx.x;
    int pq = blk & 15;
    int yp = (blk >> 4) & 15;
    int b  = blk >> 8;
    int wv = __builtin_amdgcn_readfirstlane((int)threadIdx.x >> 6);
    int lane = threadIdx.x & 63;
    int r = lane >> 5, xc = lane & 31;
    int y = yp * 2 + r;
    int p = pq * 4 + wv;

    // per-lane tap offsets (address-clamped) + clamp limit encoding validity
    int poff[9]; float lim[9];
    #pragma unroll
    for (int t = 0; t < 9; ++t) {
        int ny = y + t / 3 - 1, nx = xc + t % 3 - 1;
        bool val = ((unsigned)ny < 32u) && ((unsigned)nx < 32u);
        int nyc = min(max(ny, 0), 31), nxc = min(max(nx, 0), 31);
        poff[t] = nyc * 32 + nxc;
        lim[t] = val ? BLIM : 0.0f;
    }

    const float* xb = x + b * 65536;
    const float* tp = th1s + p * 576;
    float SC = psc[0] * INVH4;
    float acc = 0.f;

    #pragma unroll 2
    for (int c = 0; c < 64; ++c) {
        const float* xr = xb + c * 1024;
        float v[9];
        #pragma unroll
        for (int t = 0; t < 9; ++t) v[t] = xr[poff[t]];
        const float* tc = tp + c * 9;
        #pragma unroll
        for (int t = 0; t < 9; ++t) {
            float q = fmaf(v[t], SC, tc[t]);         // theta via SGPR
            q = fminf(fmaxf(q, 0.f), lim[t]);        // -> v_med3 (border folded)
            int qb = (int)q & ~3;                    // aligned byte offset
            acc += *(const float*)((const char*)lut + qb);
        }
    }

    float r0 = ls1[0] * acc;
    rawb[((b * 64 + p) * 32 + y) * 32 + xc] = r0;

    // fused BN1 partial sums: wave reduce, lane0 atomics
    float s0 = r0, q0 = r0 * r0;
    for (int s = 32; s > 0; s >>= 1) {
        s0 += __shfl_xor(s0, s);
        q0 += __shfl_xor(q0, s);
    }
    if (lane == 0) {
        atomicAdd(&sums1[p], s0);
        atomicAdd(&sums1[64 + p], q0);
    }
}

// K3: BN1 apply in place on rawb (=d_out) + activity masks. float4.
__global__ __launch_bounds__(256) void k3_bn1mask(float* __restrict__ v2,
    const float* __restrict__ sums1, const float* __restrict__ g1,
    const float* __restrict__ b1, const unsigned* __restrict__ mm,
    unsigned long long* __restrict__ masks)
{
    int i4 = blockIdx.x * 256 + threadIdx.x;       // 0..65535
    int idx = i4 * 4;
    int c = (idx >> 10) & 63;
    int b = idx >> 16;
    float m   = sums1[c] * (1.f / 4096.f);
    float var = sums1[64 + c] * (1.f / 4096.f) - m * m;
    var = fmaxf(var, 0.f);
    float rstd = rsqrtf(var + 1e-5f);
    float sc = rstd * g1[c];
    float sh = b1[c] - m * sc;
    float4 v = ((float4*)v2)[i4];
    v.x = fmaf(v.x, sc, sh); v.y = fmaf(v.y, sc, sh);
    v.z = fmaf(v.z, sc, sh); v.w = fmaf(v.w, sc, sh);
    ((float4*)v2)[i4] = v;
    float tmax = __uint_as_float(mm[0]);
    float tmin = __uint_as_float(~mm[1]);
    float wlo = tmin + BAND_LO, whi = tmax + BAND_HI;
    unsigned long long bit = 1ull << c;
    float vv[4] = {v.x, v.y, v.z, v.w};
    #pragma unroll
    for (int k = 0; k < 4; ++k) {
        if (vv[k] > wlo && vv[k] < whi)
            atomicOr(&masks[b * 1024 + ((idx + k) & 1023)], bit);
    }
}

// K4: sparse conv2. grid 1024, wave per pixel, lane = output plane. Exact f32 eval.
__global__ __launch_bounds__(256) void k4_conv2(const float* __restrict__ v2,
    const float* __restrict__ th2t, const unsigned long long* __restrict__ masks,
    const float* __restrict__ ls2, float* __restrict__ c2, float* __restrict__ sums2)
{
    int wv = __builtin_amdgcn_readfirstlane((int)threadIdx.x >> 6);
    int lane = threadIdx.x & 63;
    int P = blockIdx.x * 4 + wv;                   // 0..4095
    int b = P >> 10, rem = P & 1023;
    int y = rem >> 5, xq = rem & 31;
    float l2 = ls2[0];
    const float inv_nvt = (float)(1.0 / (1.5 * 0.026));
    float acc = 0.f;

    #pragma unroll
    for (int j = 0; j < 9; ++j) {
        int ny = y + j / 3 - 1, nx = xq + j % 3 - 1;
        if ((unsigned)ny < 32u && (unsigned)nx < 32u) {
            unsigned long long mk = masks[b * 1024 + ny * 32 + nx];
            while (mk) {
                int c = __ffsll((long long)mk) - 1;
                mk &= mk - 1;
                float v  = v2[((b * 64 + c) * 32 + ny) * 32 + nx];  // wave-uniform
                float th = th2t[(c * 9 + j) * 64 + lane];           // coalesced
                float d = v - th;
                if (d > BAND_LO && d < BAND_HI) {
                    float a1 = fminf(fmaxf(d * inv_nvt, -30.f), 30.f);
                    float a2 = fminf(fmaxf((d - 0.1f) * inv_nvt, -30.f), 30.f);
                    float s1 = __logf(1.f + __expf(a1));
                    float s2 = __logf(1.f + __expf(a2));
                    acc += (s1 * s1 - s2 * s2);
                }
            }
        }
    }
    float r2 = 0.0005625f * l2 * acc;
    c2[((b * 64 + lane) * 32 + y) * 32 + xq] = r2;

    __shared__ float ss[256], sq[256];
    ss[threadIdx.x] = r2; sq[threadIdx.x] = r2 * r2;
    __syncthreads();
    if (threadIdx.x < 64) {
        float a  = ss[threadIdx.x] + ss[threadIdx.x + 64] + ss[threadIdx.x + 128] + ss[threadIdx.x + 192];
        float qq = sq[threadIdx.x] + sq[threadIdx.x + 64] + sq[threadIdx.x + 128] + sq[threadIdx.x + 192];
        atomicAdd(&sums2[threadIdx.x], a);
        atomicAdd(&sums2[64 + threadIdx.x], qq);
    }
}

// K6: BN2 apply + residual, c2 -> d_out. float4.
__global__ __launch_bounds__(256) void k6_final(float* __restrict__ out,
    const float* __restrict__ x, const float* __restrict__ c2,
    const float* __restrict__ sums2,
    const float* __restrict__ g2, const float* __restrict__ b2)
{
    int i4 = blockIdx.x * 256 + threadIdx.x;       // 0..65535
    int idx = i4 * 4;
    int p = (idx >> 10) & 63;
    float m   = sums2[p] * (1.f / 4096.f);
    float var = sums2[64 + p] * (1.f / 4096.f) - m * m;
    var = fmaxf(var, 0.f);
    float rstd = rsqrtf(var + 1e-5f);
    float sc = rstd * g2[p];
    float sh = b2[p] - m * sc;
    float4 c = ((const float4*)c2)[i4];
    float4 xv = ((const float4*)x)[i4];
    float4 o;
    o.x = fmaf(c.x, sc, sh) + xv.x;
    o.y = fmaf(c.y, sc, sh) + xv.y;
    o.z = fmaf(c.z, sc, sh) + xv.z;
    o.w = fmaf(c.w, sc, sh) + xv.w;
    ((float4*)out)[i4] = o;
}

extern "C" void kernel_launch(void* const* d_in, const int* in_sizes, int n_in,
                              void* d_out, int out_size, void* d_ws, size_t ws_size,
                              hipStream_t stream)
{
    const float* x   = (const float*)d_in[0];
    const float* th1 = (const float*)d_in[1];
    const float* th2 = (const float*)d_in[2];
    const float* psc = (const float*)d_in[3];
    const float* psh = (const float*)d_in[4];
    const float* l1  = (const float*)d_in[5];
    const float* l2  = (const float*)d_in[6];
    const float* g1  = (const float*)d_in[7];
    const float* b1  = (const float*)d_in[8];
    const float* g2  = (const float*)d_in[9];
    const float* b2  = (const float*)d_in[10];
    float* out = (float*)d_out;
    char* ws = (char*)d_ws;
    if (ws_size < (size_t)WS_TOTAL) return;  // defensive: leave output poisoned

    float* lutg  = (float*)(ws + WS_LUT);
    float* th2t  = (float*)(ws + WS_TH2T);
    float* c2    = (float*)(ws + WS_C2);
    float* th1s  = (float*)(ws + WS_C2);     // aliases c2; dead after k1
    unsigned long long* masks = (unsigned long long*)(ws + WS_MASK);
    float* sums1 = (float*)(ws + WS_SUMS1);
    float* sums2 = (float*)(ws + WS_SUMS2);
    unsigned* mm = (unsigned*)(ws + WS_MM);

    float* rawb = out;   // conv1 raw / BN1-applied activations live in d_out

    // one memset covers masks + sums1 + sums2 + mm
    hipMemsetAsync(ws + WS_MASK, 0, WS_TOTAL - WS_MASK, stream);

    k0_prep   <<<320,  256, 0, stream>>>(th1, th2, psh, lutg, th2t, th1s, mm);
    k1_conv1  <<<1024, 256, 0, stream>>>(x, th1s, psc, l1, lutg, rawb, sums1);
    k3_bn1mask<<<256,  256, 0, stream>>>(rawb, sums1, g1, b1, mm, masks);
    k4_conv2  <<<1024, 256, 0, stream>>>(rawb, th2t, masks, l2, c2, sums2);
    k6_final  <<<256,  256, 0, stream>>>(out, x, c2, sums2, g2, b2);
}

// Round 6
// 80.960 us; speedup vs baseline: 2.4144x; 1.2257x over previous
//
#include <hip/hip_runtime.h>
#include <math.h>

// ---- nearest-neighbor LUT: 8192 floats over d in [-0.2, 1.27456), h=1.8e-4 ----
// BYTE index = (d - LO) * INVH4, clamped to [0, 32764] (per-lane limit also
// encodes border validity: invalid taps clamp to lut[0] ~= 2e-8 ~ 0).
#define NLUT    8192
#define LUT_LO  (-0.2)
#define LUT_H   (1.8e-4)
#define INVH4   22222.222222222f   // 4/LUT_H (byte-scaled index)
#define BLIM    32764.0f           // (NLUT-1)*4
#define BAND_LO (-0.35f)
#define BAND_HI (1.28f)
// static conservative theta2 window (inputs are U[2.8,4.8] by problem spec;
// wider window only adds spurious active channels, rejected by k4's exact check)
#define WLO     (2.8f + BAND_LO)   // 2.45
#define WHI     (4.8f + BAND_HI)   // 6.08

// ---- ws layout (bytes) ----
#define WS_LUT    0          // float[8192]    32768
#define WS_TH2T   32768      // float[36864]   147456 -> 180224
#define WS_C2     180224     // float[262144]  1048576 -> 1228800
                             //   th1s (float[36864]) aliases the START of C2;
                             //   th1s dead after k1, c2 written in k4.
#define WS_MASK   1228800    // u64[4096]      32768  -> 1261568
#define WS_SUMS1  1261568    // float[128]     512    -> 1262080
#define WS_SUMS2  1262080    // float[128]     512    -> 1262592
#define WS_TOTAL  1262592
#define ZERO_WORDS 8448      // (masks + sums1 + sums2) / 4

__device__ __forceinline__ double f_exact(double d) {
    const double nvt = 1.5 * 0.026;
    double a1 = d / nvt;         a1 = fmin(fmax(a1, -30.0), 30.0);
    double a2 = (d - 0.1) / nvt; a2 = fmin(fmax(a2, -30.0), 30.0);
    double s1 = log1p(exp(a1));
    double s2 = log1p(exp(a2));
    return 0.0005625 * (s1 * s1 - s2 * s2);
}

// K0: blk<32 LUT | blk<176 theta2 transpose | blk<320 th1s | blk<353 zero ws
// (stream order: all of k0 completes before k1/k3/k4 consume its outputs)
__global__ __launch_bounds__(256) void k0_prep(
    const float* __restrict__ theta1, const float* __restrict__ theta2,
    const float* __restrict__ psh,
    float* __restrict__ lutg, float* __restrict__ th2t,
    float* __restrict__ th1s, unsigned* __restrict__ zerow)
{
    int blk = blockIdx.x, tid = threadIdx.x;
    if (blk < 32) {
        int i = blk * 256 + tid;                       // 0..8191
        double d = LUT_LO + ((double)i + 0.5) * LUT_H; // cell center
        lutg[i] = (float)f_exact(d);
    } else if (blk < 176) {
        int i = (blk - 32) * 256 + tid;                // 0..36863
        int p = i & 63, k = i >> 6;
        th2t[k * 64 + p] = theta2[p * 576 + k];
    } else if (blk < 320) {
        int i = (blk - 176) * 256 + tid;               // 0..36863
        // byte-index term: (psh - LO - theta1) * INVH4 ; x term added in k1
        th1s[i] = (psh[0] - (float)LUT_LO - theta1[i]) * INVH4;
    } else {
        int i = (blk - 320) * 256 + tid;               // 0..8447
        zerow[i] = 0u;
    }
}

// K1: dense conv1. grid 1024 = b(4) x yp(16) x pq(16); block = 512 thr = 8 waves:
// wave w -> plane pq*4 + (w&3), c-half (w>>2). 4 blocks/CU -> 32 waves/CU.
// Raw-x coalesced loads, wave-uniform pre-scaled theta -> s_loads, unconditional
// clamped LUT gathers (border folded into per-lane clamp limit). Halves combined
// via LDS; BN1 partial sums fused (wave reduce + lane0 atomics).
__global__ __launch_bounds__(512, 8) void k1_conv1(
    const float* __restrict__ x, const float* __restrict__ th1s,
    const float* __restrict__ psc, const float* __restrict__ ls1,
    const float* __restrict__ lutg,
    float* __restrict__ rawb, float* __restrict__ sums1)
{
    __shared__ float lut[NLUT];
    __shared__ float part[256];
    {
        const float4* s = (const float4*)lutg;
        float4* d = (float4*)lut;
        for (int i = threadIdx.x; i < NLUT / 4; i += 512) d[i] = s[i];
    }
    __syncthreads();

    int blk = blockIdx.x;
    int pq = blk & 15;
    int yp = (blk >> 4) & 15;
    int b  = blk >> 8;
    int wv   = __builtin_amdgcn_readfirstlane((int)threadIdx.x >> 6);
    int lane = threadIdx.x & 63;
    int r = lane >> 5, xc = lane & 31;
    int y = yp * 2 + r;
    int p  = pq * 4 + (wv & 3);
    int c0 = (wv >> 2) * 32;

    // per-lane tap offsets (address-clamped) + clamp limit encoding validity
    int poff[9]; float lim[9];
    #pragma unroll
    for (int t = 0; t < 9; ++t) {
        int ny = y + t / 3 - 1, nx = xc + t % 3 - 1;
        bool val = ((unsigned)ny < 32u) && ((unsigned)nx < 32u);
        int nyc = min(max(ny, 0), 31), nxc = min(max(nx, 0), 31);
        poff[t] = nyc * 32 + nxc;
        lim[t] = val ? BLIM : 0.0f;
    }

    const float* xb = x + b * 65536 + c0 * 1024;
    const float* tp = th1s + p * 576 + c0 * 9;
    float SC = psc[0] * INVH4;
    float acc = 0.f;

    #pragma unroll 2
    for (int c = 0; c < 32; ++c) {
        const float* xr = xb + c * 1024;
        float v[9];
        #pragma unroll
        for (int t = 0; t < 9; ++t) v[t] = xr[poff[t]];
        const float* tc = tp + c * 9;
        #pragma unroll
        for (int t = 0; t < 9; ++t) {
            float q = fmaf(v[t], SC, tc[t]);         // theta via SGPR
            q = fminf(fmaxf(q, 0.f), lim[t]);        // -> v_med3 (border folded)
            int qb = (int)q & ~3;                    // aligned byte offset
            acc += *(const float*)((const char*)lut + qb);
        }
    }

    // combine c-halves: upper half deposits, lower half finalizes
    if (wv >= 4) part[(wv & 3) * 64 + lane] = acc;
    __syncthreads();
    if (wv < 4) {
        acc += part[wv * 64 + lane];
        float r0 = ls1[0] * acc;
        rawb[((b * 64 + p) * 32 + y) * 32 + xc] = r0;

        float s0 = r0, q0 = r0 * r0;
        for (int s = 32; s > 0; s >>= 1) {
            s0 += __shfl_xor(s0, s);
            q0 += __shfl_xor(q0, s);
        }
        if (lane == 0) {
            atomicAdd(&sums1[p], s0);
            atomicAdd(&sums1[64 + p], q0);
        }
    }
}

// K3: BN1 apply in place on rawb (=d_out) + activity masks. float4.
__global__ __launch_bounds__(256) void k3_bn1mask(float* __restrict__ v2,
    const float* __restrict__ sums1, const float* __restrict__ g1,
    const float* __restrict__ b1, unsigned long long* __restrict__ masks)
{
    int i4 = blockIdx.x * 256 + threadIdx.x;       // 0..65535
    int idx = i4 * 4;
    int c = (idx >> 10) & 63;
    int b = idx >> 16;
    float m   = sums1[c] * (1.f / 4096.f);
    float var = sums1[64 + c] * (1.f / 4096.f) - m * m;
    var = fmaxf(var, 0.f);
    float rstd = rsqrtf(var + 1e-5f);
    float sc = rstd * g1[c];
    float sh = b1[c] - m * sc;
    float4 v = ((float4*)v2)[i4];
    v.x = fmaf(v.x, sc, sh); v.y = fmaf(v.y, sc, sh);
    v.z = fmaf(v.z, sc, sh); v.w = fmaf(v.w, sc, sh);
    ((float4*)v2)[i4] = v;
    unsigned long long bit = 1ull << c;
    float vv[4] = {v.x, v.y, v.z, v.w};
    #pragma unroll
    for (int k = 0; k < 4; ++k) {
        if (vv[k] > WLO && vv[k] < WHI)
            atomicOr(&masks[b * 1024 + ((idx + k) & 1023)], bit);
    }
}

// K4: sparse conv2. grid 1024, wave per pixel, lane = output plane. Exact f32 eval.
__global__ __launch_bounds__(256) void k4_conv2(const float* __restrict__ v2,
    const float* __restrict__ th2t, const unsigned long long* __restrict__ masks,
    const float* __restrict__ ls2, float* __restrict__ c2, float* __restrict__ sums2)
{
    int wv = __builtin_amdgcn_readfirstlane((int)threadIdx.x >> 6);
    int lane = threadIdx.x & 63;
    int P = blockIdx.x * 4 + wv;                   // 0..4095
    int b = P >> 10, rem = P & 1023;
    int y = rem >> 5, xq = rem & 31;
    float l2 = ls2[0];
    const float inv_nvt = (float)(1.0 / (1.5 * 0.026));
    float acc = 0.f;

    #pragma unroll
    for (int j = 0; j < 9; ++j) {
        int ny = y + j / 3 - 1, nx = xq + j % 3 - 1;
        if ((unsigned)ny < 32u && (unsigned)nx < 32u) {
            unsigned long long mk = masks[b * 1024 + ny * 32 + nx];
            while (mk) {
                int c = __ffsll((long long)mk) - 1;
                mk &= mk - 1;
                float v  = v2[((b * 64 + c) * 32 + ny) * 32 + nx];  // wave-uniform
                float th = th2t[(c * 9 + j) * 64 + lane];           // coalesced
                float d = v - th;
                if (d > BAND_LO && d < BAND_HI) {
                    float a1 = fminf(fmaxf(d * inv_nvt, -30.f), 30.f);
                    float a2 = fminf(fmaxf((d - 0.1f) * inv_nvt, -30.f), 30.f);
                    float s1 = __logf(1.f + __expf(a1));
                    float s2 = __logf(1.f + __expf(a2));
                    acc += (s1 * s1 - s2 * s2);
                }
            }
        }
    }
    float r2 = 0.0005625f * l2 * acc;
    c2[((b * 64 + lane) * 32 + y) * 32 + xq] = r2;

    __shared__ float ss[256], sq[256];
    ss[threadIdx.x] = r2; sq[threadIdx.x] = r2 * r2;
    __syncthreads();
    if (threadIdx.x < 64) {
        float a  = ss[threadIdx.x] + ss[threadIdx.x + 64] + ss[threadIdx.x + 128] + ss[threadIdx.x + 192];
        float qq = sq[threadIdx.x] + sq[threadIdx.x + 64] + sq[threadIdx.x + 128] + sq[threadIdx.x + 192];
        atomicAdd(&sums2[threadIdx.x], a);
        atomicAdd(&sums2[64 + threadIdx.x], qq);
    }
}

// K6: BN2 apply + residual, c2 -> d_out. float4.
__global__ __launch_bounds__(256) void k6_final(float* __restrict__ out,
    const float* __restrict__ x, const float* __restrict__ c2,
    const float* __restrict__ sums2,
    const float* __restrict__ g2, const float* __restrict__ b2)
{
    int i4 = blockIdx.x * 256 + threadIdx.x;       // 0..65535
    int idx = i4 * 4;
    int p = (idx >> 10) & 63;
    float m   = sums2[p] * (1.f / 4096.f);
    float var = sums2[64 + p] * (1.f / 4096.f) - m * m;
    var = fmaxf(var, 0.f);
    float rstd = rsqrtf(var + 1e-5f);
    float sc = rstd * g2[p];
    float sh = b2[p] - m * sc;
    float4 c = ((const float4*)c2)[i4];
    float4 xv = ((const float4*)x)[i4];
    float4 o;
    o.x = fmaf(c.x, sc, sh) + xv.x;
    o.y = fmaf(c.y, sc, sh) + xv.y;
    o.z = fmaf(c.z, sc, sh) + xv.z;
    o.w = fmaf(c.w, sc, sh) + xv.w;
    ((float4*)out)[i4] = o;
}

extern "C" void kernel_launch(void* const* d_in, const int* in_sizes, int n_in,
                              void* d_out, int out_size, void* d_ws, size_t ws_size,
                              hipStream_t stream)
{
    const float* x   = (const float*)d_in[0];
    const float* th1 = (const float*)d_in[1];
    const float* th2 = (const float*)d_in[2];
    const float* psc = (const float*)d_in[3];
    const float* psh = (const float*)d_in[4];
    const float* l1  = (const float*)d_in[5];
    const float* l2  = (const float*)d_in[6];
    const float* g1  = (const float*)d_in[7];
    const float* b1  = (const float*)d_in[8];
    const float* g2  = (const float*)d_in[9];
    const float* b2  = (const float*)d_in[10];
    float* out = (float*)d_out;
    char* ws = (char*)d_ws;
    if (ws_size < (size_t)WS_TOTAL) return;  // defensive: leave output poisoned

    float* lutg  = (float*)(ws + WS_LUT);
    float* th2t  = (float*)(ws + WS_TH2T);
    float* c2    = (float*)(ws + WS_C2);
    float* th1s  = (float*)(ws + WS_C2);     // aliases c2; dead after k1
    unsigned long long* masks = (unsigned long long*)(ws + WS_MASK);
    float* sums1 = (float*)(ws + WS_SUMS1);
    float* sums2 = (float*)(ws + WS_SUMS2);
    unsigned* zerow = (unsigned*)(ws + WS_MASK);  // masks+sums zeroed by k0

    float* rawb = out;   // conv1 raw / BN1-applied activations live in d_out

    k0_prep   <<<353,  256, 0, stream>>>(th1, th2, psh, lutg, th2t, th1s, zerow);
    k1_conv1  <<<1024, 512, 0, stream>>>(x, th1s, psc, l1, lutg, rawb, sums1);
    k3_bn1mask<<<256,  256, 0, stream>>>(rawb, sums1, g1, b1, masks);
    k4_conv2  <<<1024, 256, 0, stream>>>(rawb, th2t, masks, l2, c2, sums2);
    k6_final  <<<256,  256, 0, stream>>>(out, x, c2, sums2, g2, b2);
}